// Round 3
// baseline (410.568 us; speedup 1.0000x reference)
//
#include <hip/hip_runtime.h>
#include <hip/hip_bf16.h>
#include <hip/hip_fp8.h>
#include <cstdint>
#include <cstddef>

// ---------------- problem constants ----------------
#define M_TOK 4096          // B*S = 4*1024 tokens
#define HID   1024
#define NHEAD 16002
#define NHEAD_PAD 16128     // 126*128
#define P0    256
#define N0    12000
#define N0_PAD 12032        // 94*128
#define P1    64
#define N1    8000
#define N1_PAD 8192         // 64*128 (padded to even tile count for swizzle)
#define PFUSE 384           // fused proj width: 256 + 128(pad of 64)
#define PREAL 320           // real cols in fused proj: 256 + 64

typedef unsigned char u8;
typedef float f32x16 __attribute__((ext_vector_type(16)));
typedef int   i32x4  __attribute__((ext_vector_type(4)));
typedef int   i32x8  __attribute__((ext_vector_type(8)));

// async global->LDS, 16B per lane; lds ptr = wave-uniform base, HW scatters lane*16.
__device__ __forceinline__ void load16(const void* g, void* l) {
    __builtin_amdgcn_global_load_lds(
        (__attribute__((address_space(1))) void*)g,
        (__attribute__((address_space(3))) void*)l,
        16, 0, 0);
}

__device__ __forceinline__ u8 to_e4m3(float f) {
    __hip_fp8_e4m3 h(f);
    return (u8)h.__x;
}

// =====================================================================
// Unified MX-fp8 GEMM body: C = A(M x K, lda) * BT(N x K, ldb)^T
// mfma_scale_f32_32x32x64_f8f6f4; A-scale 1.0, B-scale 2^-5.
// Block 128x128, BK=64, 4 waves 2x2, wave 64x64 via 2x2 MFMAs of 32x32.
//
// Round-3 design: double-buffered pipelining at UNCHANGED 32 KB LDS
// (BK halved to 64 -> 8 KB per matrix per buffer; 2 buffers).
// Per k-step: stage(next tile, other buf) -> counted s_waitcnt vmcnt(4)
// (current tile's 4 loads; NEVER a full drain in the loop) -> s_barrier ->
// 8x ds_read_b128 + 4x MFMA -> lgkmcnt(0) -> s_barrier. The HBM/L2 round
// trip of tile t+1 hides under tile t's compute; occupancy stays 4
// blocks/CU (64 VGPR + 64 AGPR budget unchanged).
//
// LDS layout per matrix tile: 128 rows x 4 granules(16B). Swizzle:
// phys_granule_in_row = g ^ ((row>>1)&3). Fragment ds_reads are then
// conflict-free: each 8-lane group covers all 32 banks exactly once
// (hand-verified for both K-chunks). Staging uses the inverse (same XOR)
// on the per-lane GLOBAL address; LDS write side stays linear as
// global_load_lds requires.
//
// 32x32x64 operand layout (analog of R5-verified 16x16x128):
//   A: lane l holds row = l&31, K-bytes [(l>>5)*32, +32) in 8 VGPRs.
//   B: same with col = l&31.
//   C/D: col = lane&31, row = (reg&3) + 8*(reg>>2) + 4*(lane>>5).
// =====================================================================
template <bool LSEP>
__device__ __forceinline__ void gemm_body(
        const u8* __restrict__ A, int lda, const u8* __restrict__ BT, int ldb,
        const float* __restrict__ bias, int K, int realN,
        const int* __restrict__ tgt, float* __restrict__ sumexp, float* __restrict__ lab,
        u8* __restrict__ out, int ldo, int m0, int n0,
        u8* As, u8* Bs) {
    const int tid  = threadIdx.x;
    const int lane = tid & 63;
    const int wave = tid >> 6;
    const int wm = wave >> 1, wn = wave & 1;
    const int h = lane >> 5;          // K-chunk (operands) / row-half (C/D)
    const int c = lane & 31;          // row (A) / col (B, C/D) within 32
    const int s = (c >> 1) & 3;       // frag-read swizzle term

    // staging: per matrix 512 granules (128 rows x 4); 2 wave-loads/wave.
    // LDS physical granule pg = wave*128 + p*64 + lane (linear write);
    // source global granule: row = pg>>2, g = (pg&3) ^ ((row>>1)&3).
    int aofs[2], bofs[2], lbase[2];
    #pragma unroll
    for (int p = 0; p < 2; p++) {
        int pg = wave * 128 + p * 64 + lane;
        int row = pg >> 2;
        int g = (pg & 3) ^ ((row >> 1) & 3);
        aofs[p]  = row * lda + g * 16;
        bofs[p]  = row * ldb + g * 16;
        lbase[p] = (wave * 128 + p * 64) * 16;   // wave-uniform LDS byte offset
    }

    f32x16 acc[2][2];
    #pragma unroll
    for (int mt = 0; mt < 2; mt++)
        #pragma unroll
        for (int nt = 0; nt < 2; nt++)
            acc[mt][nt] = (f32x16)(0.0f);

    const u8* Ab = A  + (size_t)m0 * lda;
    const u8* Bb = BT + (size_t)n0 * ldb;

    auto stage = [&](int buf, int k0) {
        const int lofs = buf * 8192;
        #pragma unroll
        for (int p = 0; p < 2; p++) {
            load16(Ab + k0 + aofs[p], As + lofs + lbase[p]);
            load16(Bb + k0 + bofs[p], Bs + lofs + lbase[p]);
        }
    };

    // fragment LDS byte offsets (buf 0, mt/nt 0); +t*2048 per 32-row subtile,
    // +8192 per buffer. row = base + c; swizzled granule = g ^ s.
    const int aLo = ((wm * 64 + c) * 4 + ((2 * h)     ^ s)) * 16;
    const int aHi = ((wm * 64 + c) * 4 + ((2 * h + 1) ^ s)) * 16;
    const int bLo = ((wn * 64 + c) * 4 + ((2 * h)     ^ s)) * 16;
    const int bHi = ((wn * 64 + c) * 4 + ((2 * h + 1) ^ s)) * 16;

    union Frag { struct { i32x4 lo, hi; } half; i32x8 v; };

    auto compute = [&](int buf) {
        const u8* Ac = As + buf * 8192;
        const u8* Bc = Bs + buf * 8192;
        Frag fa[2], fb[2];
        #pragma unroll
        for (int t = 0; t < 2; t++) {
            fa[t].half.lo = *reinterpret_cast<const i32x4*>(Ac + aLo + t * 2048);
            fa[t].half.hi = *reinterpret_cast<const i32x4*>(Ac + aHi + t * 2048);
            fb[t].half.lo = *reinterpret_cast<const i32x4*>(Bc + bLo + t * 2048);
            fb[t].half.hi = *reinterpret_cast<const i32x4*>(Bc + bHi + t * 2048);
        }
        #pragma unroll
        for (int mt = 0; mt < 2; mt++)
            #pragma unroll
            for (int nt = 0; nt < 2; nt++)
                acc[mt][nt] = __builtin_amdgcn_mfma_scale_f32_32x32x64_f8f6f4(
                    fa[mt].v, fb[nt].v, acc[mt][nt],
                    0, 0,                      // cbsz/blgp = fp8 e4m3
                    0, 0x7F7F7F7F,             // A scale: 2^0
                    0, 0x7A7A7A7A);            // B scale: 2^-5
    };

    // -------- pipelined K-loop (counted vmcnt, raw barriers) --------
    stage(0, 0);
    int cur = 0;
    for (int k0 = 0; k0 < K; k0 += 64, cur ^= 1) {
        if (k0 + 64 < K) {
            stage(cur ^ 1, k0 + 64);                         // prefetch next tile
            asm volatile("s_waitcnt vmcnt(4)" ::: "memory"); // wait CURRENT tile's 4 only
        } else {
            asm volatile("s_waitcnt vmcnt(0)" ::: "memory"); // last tile: drain
        }
        asm volatile("s_barrier" ::: "memory");              // all waves' writes landed
        compute(cur);
        asm volatile("s_waitcnt lgkmcnt(0)" ::: "memory");   // my ds_reads retired
        asm volatile("s_barrier" ::: "memory");              // safe to overwrite buf
    }

    // ---- epilogue: C/D 32x32 layout: col = c, row = (reg&3)+8*(reg>>2)+4*h
    int colg[2]; float bias_v[2];
    #pragma unroll
    for (int nt = 0; nt < 2; nt++) {
        colg[nt] = n0 + wn * 64 + nt * 32 + c;
        bias_v[nt] = (colg[nt] < realN) ? bias[colg[nt]] : 0.0f;
    }

    #pragma unroll
    for (int mt = 0; mt < 2; mt++) {
        int rowb = m0 + wm * 64 + mt * 32 + 4 * h;
        #pragma unroll
        for (int reg = 0; reg < 16; reg++) {
            int tok = rowb + (reg & 3) + 8 * (reg >> 2);
            if constexpr (LSEP) {
                int tg = tgt[tok];
                float sum = 0.0f;
                #pragma unroll
                for (int nt = 0; nt < 2; nt++) {
                    if (colg[nt] < realN) {
                        float logit = acc[mt][nt][reg] + bias_v[nt];
                        sum += __expf(logit);
                        if (colg[nt] == tg) atomicAdd(&lab[tok], logit);
                    }
                }
                sum += __shfl_xor(sum, 1);
                sum += __shfl_xor(sum, 2);
                sum += __shfl_xor(sum, 4);
                sum += __shfl_xor(sum, 8);
                sum += __shfl_xor(sum, 16);   // stays within each 32-lane half
                if (c == 0) atomicAdd(&sumexp[tok], sum);
            } else {
                #pragma unroll
                for (int nt = 0; nt < 2; nt++)
                    out[(size_t)tok * ldo + colg[nt]] = to_e4m3(acc[mt][nt][reg] + bias_v[nt]);
            }
        }
    }
}

// ---------------- proj GEMM (store epilogue) ----------------
__launch_bounds__(256, 4)
__global__ void gemm_proj(const u8* __restrict__ A, const u8* __restrict__ BT,
                          const float* __restrict__ bias, u8* __restrict__ out) {
    __shared__ __align__(16) u8 As[16384];
    __shared__ __align__(16) u8 Bs[16384];
    gemm_body<false>(A, HID, BT, HID, bias, HID, PREAL,
                     nullptr, nullptr, nullptr, out, PFUSE,
                     blockIdx.x * 128, blockIdx.y * 128, As, Bs);
}

// ---------------- fused LSE GEMM: head + tail0 + tail1 in one dispatch ----------------
struct Seg {
    const u8* A; int lda;
    const u8* BT; int ldb;
    const float* bias; int K; int realN;
    const int* tgt; float* sumexp; float* lab;
    int nblk;   // 32 m-tiles x NT n-tiles, NT even; nblk % 64 == 0
};

__launch_bounds__(256, 4)
__global__ void gemm_lse3(Seg s0, Seg s1, Seg s2) {
    __shared__ __align__(16) u8 As[16384];
    __shared__ __align__(16) u8 Bs[16384];
    int b = blockIdx.x;
    Seg s; int rel;
    if (b < s0.nblk)                { s = s0; rel = b; }
    else if (b < s0.nblk + s1.nblk) { s = s1; rel = b - s0.nblk; }
    else                            { s = s2; rel = b - s0.nblk - s1.nblk; }
    // L2-locality swizzle: 64-block groups = 32 m-tiles x 2 n-tiles.
    int pair = rel >> 6, inner = rel & 63;
    int m0 = (inner >> 1) * 128;
    int n0 = (pair * 2 + (inner & 1)) * 128;
    gemm_body<true>(s.A, s.lda, s.BT, s.ldb, s.bias, s.K, s.realN,
                    s.tgt, s.sumexp, s.lab, nullptr, 0, m0, n0, As, Bs);
}

// =====================================================================
// prep: all casts/transposes/init fused into one dispatch (branch by range)
// 64x64 transpose tiles: float2 row reads (8B/lane; float4 blocked by
// N=16002 row alignment), 16B/lane fp8 stores.
// =====================================================================
__device__ __forceinline__ void do_transpose(const float* __restrict__ W, u8* __restrict__ WT,
                                             int K, int N, int Kpad, float scale,
                                             int bx, int by, float (*tile)[65]) {
    int n0 = bx * 64, k0 = by * 64;
    int c2 = threadIdx.x & 31;           // column pair 0..31
    int rg = threadIdx.x >> 5;           // row group 0..7
    int n = n0 + c2 * 2;
    #pragma unroll
    for (int j = 0; j < 8; j++) {
        int k = k0 + rg + j * 8;
        float2 v;
        if (k < K && n + 1 < N) {
            v = *reinterpret_cast<const float2*>(&W[(size_t)k * N + n]);
        } else {
            v.x = (k < K && n     < N) ? W[(size_t)k * N + n]     : 0.0f;
            v.y = (k < K && n + 1 < N) ? W[(size_t)k * N + n + 1] : 0.0f;
        }
        tile[rg + j * 8][c2 * 2]     = v.x * scale;
        tile[rg + j * 8][c2 * 2 + 1] = v.y * scale;
    }
    __syncthreads();
    int nn = threadIdx.x >> 2, kb = (threadIdx.x & 3) * 16;   // nn 0..63, kb 0/16/32/48
    union { u8 b[16]; uint4 u; } v;
    #pragma unroll
    for (int j = 0; j < 16; j++) v.b[j] = to_e4m3(tile[kb + j][nn]);
    *reinterpret_cast<uint4*>(WT + (size_t)(n0 + nn) * Kpad + k0 + kb) = v.u;
}

#define NBT_HEAD 4032   // 252 x 16
#define NBT_CAST 1024
#define NBT_T0W   752   // 188 x 4
#define NBT_T1W   256   // 128 x 2
#define NBT_T0P    64   // 4 x 16
#define NBT_T1P    32   // 2 x 16
#define NBT_INIT   16

__global__ void prep_kernel(const float* __restrict__ inp, const int* __restrict__ labels,
                            const float* __restrict__ head_W,
                            const float* __restrict__ t0_pW, const float* __restrict__ t0_pb,
                            const float* __restrict__ t0_W,
                            const float* __restrict__ t1_pW, const float* __restrict__ t1_pb,
                            const float* __restrict__ t1_W,
                            u8* __restrict__ inp_f8, u8* __restrict__ headW8,
                            u8* __restrict__ fpW8, u8* __restrict__ t0W8, u8* __restrict__ t1W8,
                            float* __restrict__ acc6, int* __restrict__ tgts,
                            float* __restrict__ pbias, float* __restrict__ out) {
    __shared__ float tile[64][65];
    int b = blockIdx.x;
    if (b < NBT_HEAD) {
        do_transpose(head_W, headW8, HID, NHEAD, HID, 32.0f, b % 252, b / 252, tile);
    } else if (b < NBT_HEAD + NBT_CAST) {
        int r = b - NBT_HEAD;
        int i = r * 256 + threadIdx.x;          // i < 262144 = M_TOK*HID/4
        float4 v = reinterpret_cast<const float4*>(inp)[i];
        uchar4 o8;
        o8.x = to_e4m3(v.x); o8.y = to_e4m3(v.y); o8.z = to_e4m3(v.z); o8.w = to_e4m3(v.w);
        reinterpret_cast<uchar4*>(inp_f8)[i] = o8;
    } else if (b < NBT_HEAD + NBT_CAST + NBT_T0W) {
        int r = b - (NBT_HEAD + NBT_CAST);
        do_transpose(t0_W, t0W8, P0, N0, P0, 32.0f, r % 188, r / 188, tile);
    } else if (b < NBT_HEAD + NBT_CAST + NBT_T0W + NBT_T1W) {
        int r = b - (NBT_HEAD + NBT_CAST + NBT_T0W);
        do_transpose(t1_W, t1W8, P1, N1, 128, 32.0f, r % 128, r / 128, tile);
    } else if (b < NBT_HEAD + NBT_CAST + NBT_T0W + NBT_T1W + NBT_T0P) {
        int r = b - (NBT_HEAD + NBT_CAST + NBT_T0W + NBT_T1W);
        do_transpose(t0_pW, fpW8, HID, P0, HID, 32.0f, r % 4, r / 4, tile);
    } else if (b < NBT_HEAD + NBT_CAST + NBT_T0W + NBT_T1W + NBT_T0P + NBT_T1P) {
        int r = b - (NBT_HEAD + NBT_CAST + NBT_T0W + NBT_T1W + NBT_T0P);
        do_transpose(t1_pW, fpW8 + 256 * HID, HID, P1, HID, 32.0f, r % 2, r / 2, tile);
    } else {
        int r = b - (NBT_HEAD + NBT_CAST + NBT_T0W + NBT_T1W + NBT_T0P + NBT_T1P);
        int t = r * 256 + threadIdx.x;          // t < 4096
        for (int j = t; j < 6 * M_TOK; j += M_TOK) acc6[j] = 0.0f;
        if (t == 0) out[0] = 0.0f;
        if (t < PFUSE) pbias[t] = (t < 256) ? t0_pb[t] : ((t < PREAL) ? t1_pb[t - 256] : 0.0f);
        int lbl = labels[t];
        tgts[t]             = (lbl < 16000) ? lbl : ((lbl < 28000) ? 16000 : 16001);
        int t0 = lbl - 16000; t0 = t0 < 0 ? 0 : (t0 > 11999 ? 11999 : t0);
        int t1 = lbl - 28000; t1 = t1 < 0 ? 0 : (t1 > 7999  ? 7999  : t1);
        tgts[M_TOK + t]     = t0;
        tgts[2 * M_TOK + t] = t1;
    }
}

// ---------------- finalize: per-token loss, mask, mean ----------------
__global__ void finalize_kernel(const int* __restrict__ labels, const float* __restrict__ acc6,
                                float* __restrict__ out) {
    int t = blockIdx.x * blockDim.x + threadIdx.x;   // 4096 threads
    const float* sumH = acc6;
    const float* labH = acc6 + M_TOK;
    const float* sum0 = acc6 + 2 * M_TOK;
    const float* lab0 = acc6 + 3 * M_TOK;
    const float* sum1 = acc6 + 4 * M_TOK;
    const float* lab1 = acc6 + 5 * M_TOK;
    int lbl = labels[t];
    float l = 0.0f;
    if (lbl != 0) {
        l = logf(sumH[t]) - labH[t];
        if (lbl >= 16000 && lbl < 28000) l += logf(sum0[t]) - lab0[t];
        else if (lbl >= 28000)           l += logf(sum1[t]) - lab1[t];
    }
    l *= (1.0f / (float)M_TOK);
    #pragma unroll
    for (int off = 1; off < 64; off <<= 1) l += __shfl_xor(l, off);
    __shared__ float red[4];
    if ((threadIdx.x & 63) == 0) red[threadIdx.x >> 6] = l;
    __syncthreads();
    if (threadIdx.x == 0) atomicAdd(out, red[0] + red[1] + red[2] + red[3]);
}

// ---------------- host launcher ----------------
extern "C" void kernel_launch(void* const* d_in, const int* in_sizes, int n_in,
                              void* d_out, int out_size, void* d_ws, size_t ws_size,
                              hipStream_t stream) {
    const float* inp    = (const float*)d_in[0];
    const int*   labels = (const int*)  d_in[1];
    const float* head_W = (const float*)d_in[2];
    const float* head_b = (const float*)d_in[3];
    const float* t0_pW  = (const float*)d_in[4];
    const float* t0_pb  = (const float*)d_in[5];
    const float* t0_W   = (const float*)d_in[6];
    const float* t0_b   = (const float*)d_in[7];
    const float* t1_pW  = (const float*)d_in[8];
    const float* t1_pb  = (const float*)d_in[9];
    const float* t1_W   = (const float*)d_in[10];
    const float* t1_b   = (const float*)d_in[11];
    float* out = (float*)d_out;

    char* ws = (char*)d_ws;
    size_t off = 0;
    auto alloc = [&](size_t bytes) { char* p = ws + off; off += (bytes + 255) & ~(size_t)255; return p; };
    u8*    inp_f8  = (u8*)   alloc((size_t)M_TOK * HID);
    u8*    headW8  = (u8*)   alloc((size_t)NHEAD_PAD * HID);
    u8*    fpW8    = (u8*)   alloc((size_t)PFUSE * HID);
    u8*    t0W8    = (u8*)   alloc((size_t)N0_PAD * P0);
    u8*    t1W8    = (u8*)   alloc((size_t)N1_PAD * 128);
    u8*    proj8   = (u8*)   alloc((size_t)M_TOK * PFUSE);
    float* acc6    = (float*)alloc(6 * M_TOK * 4);
    int*   tgts    = (int*)  alloc(3 * M_TOK * 4);
    float* pbias   = (float*)alloc(PFUSE * 4);

    // stage 1: all conversions / transposes / init in one dispatch
    int nb = NBT_HEAD + NBT_CAST + NBT_T0W + NBT_T1W + NBT_T0P + NBT_T1P + NBT_INIT;
    prep_kernel<<<nb, 256, 0, stream>>>(inp, labels, head_W, t0_pW, t0_pb, t0_W,
                                        t1_pW, t1_pb, t1_W,
                                        inp_f8, headW8, fpW8, t0W8, t1W8,
                                        acc6, tgts, pbias, out);

    // stage 2: fused tail projections -> fp8 [M_TOK x 384]
    gemm_proj<<<dim3(M_TOK / 128, PFUSE / 128), 256, 0, stream>>>(inp_f8, fpW8, pbias, proj8);

    // stage 3: all three LSE GEMMs in one dispatch (head first = longest)
    Seg s0{inp_f8,      HID,   headW8, HID, head_b, HID, NHEAD, tgts,             acc6,             acc6 + M_TOK,     32 * (NHEAD_PAD / 128)};
    Seg s1{proj8,       PFUSE, t0W8,   P0,  t0_b,   P0,  N0,    tgts + M_TOK,     acc6 + 2 * M_TOK, acc6 + 3 * M_TOK, 32 * (N0_PAD / 128)};
    Seg s2{proj8 + 256, PFUSE, t1W8,   128, t1_b,   128, N1,    tgts + 2 * M_TOK, acc6 + 4 * M_TOK, acc6 + 5 * M_TOK, 32 * (N1_PAD / 128)};
    gemm_lse3<<<s0.nblk + s1.nblk + s2.nblk, 256, 0, stream>>>(s0, s1, s2);

    // stage 4: reduce to scalar mean
    finalize_kernel<<<M_TOK / 256, 256, 0, stream>>>(labels, acc6, out);
}